// Round 8
// baseline (86.665 us; speedup 1.0000x reference)
//
#include <hip/hip_runtime.h>
#include <math.h>

#define NQ 8
#define NDEPTH 3
#define FEAT 512
#define NCLS 10
#define NBATCH 8192

// ---------------------------------------------------------------------------
// Single fused kernel (R7 structure, 83.7 µs, absmax 3.9e-3) with the
// mask-16 / mask-32 cross-lane rotation gates moved from the DS pipe
// (ds_bpermute) onto the VALU pipe via gfx950 v_permlane{16,32}_swap_b32.
// State layout: amp index = lane*4 + j ; j = qubits 0,1 ; lane bits = qubits 2..7.
// ---------------------------------------------------------------------------

typedef unsigned v2u __attribute__((ext_vector_type(2)));

// partner value at lane^16, VALU-pipe (bit-exact replacement for __shfl_xor(v,16))
__device__ __forceinline__ float xor16_val(float v, int lane) {
#if __has_builtin(__builtin_amdgcn_permlane16_swap)
    v2u r = __builtin_amdgcn_permlane16_swap(__float_as_uint(v), __float_as_uint(v),
                                             false, false);
    // r[0]: lanes 16-31 <- v[0:15], 48-63 <- v[32:47]
    // r[1]: lanes  0-15 <- v[16:31], 32-47 <- v[48:63]
    return __uint_as_float((lane & 16) ? r[0] : r[1]);
#else
    return __shfl_xor(v, 16);
#endif
}

// partner value at lane^32, VALU-pipe
__device__ __forceinline__ float xor32_val(float v, int lane) {
#if __has_builtin(__builtin_amdgcn_permlane32_swap)
    v2u r = __builtin_amdgcn_permlane32_swap(__float_as_uint(v), __float_as_uint(v),
                                             false, false);
    // r[0]: lanes 32-63 <- v[0:31] ; r[1]: lanes 0-31 <- v[32:63]
    return __uint_as_float((lane & 32) ? r[0] : r[1]);
#else
    return __shfl_xor(v, 32);
#endif
}

// DPP helpers (HW-verified R2..R7)
template <int CTRL, int ROW_MASK>
__device__ __forceinline__ float dpp_term(float v) {
    return __int_as_float(__builtin_amdgcn_update_dpp(
        0, __float_as_int(v), CTRL, ROW_MASK, 0xf, true));
}

__device__ __forceinline__ float wave_sum_bcast(float v) {
    v += dpp_term<0x111, 0xf>(v); // row_shr:1
    v += dpp_term<0x112, 0xf>(v); // row_shr:2
    v += dpp_term<0x114, 0xf>(v); // row_shr:4
    v += dpp_term<0x118, 0xf>(v); // row_shr:8
    v += dpp_term<0x142, 0xa>(v); // row_bcast15
    v += dpp_term<0x143, 0xc>(v); // row_bcast31
    return __int_as_float(__builtin_amdgcn_readlane(__float_as_int(v), 63));
}

__device__ __forceinline__ float bcastlane(float v, int srclane) {
    return __int_as_float(__builtin_amdgcn_readlane(__float_as_int(v), srclane));
}

template <int CTRL>
__device__ __forceinline__ float dpp_xor(float v) {
    return __int_as_float(__builtin_amdgcn_update_dpp(
        0, __float_as_int(v), CTRL, 0xf, 0xf, true));
}

__device__ __forceinline__ float fast_tanh(float v) {
    float e = __expf(2.f * v);
    return 1.f - 2.f / (e + 1.f);
}

// Gate application (HW-verified R2..R7)
__device__ __forceinline__ void cgate_pair(const float* __restrict__ u,
        float& r0, float& i0, float& r1, float& i1) {
    float nr0 = u[0]*r0 - u[1]*i0 + u[2]*r1 - u[3]*i1;
    float ni0 = u[0]*i0 + u[1]*r0 + u[2]*i1 + u[3]*r1;
    float nr1 = u[4]*r0 - u[5]*i0 + u[6]*r1 - u[7]*i1;
    float ni1 = u[4]*i0 + u[5]*r0 + u[6]*i1 + u[7]*r1;
    r0 = nr0; i0 = ni0; r1 = nr1; i1 = ni1;
}

__device__ __forceinline__ void cgate_shfl(const float* __restrict__ u, int bit,
        int mask, float (&re)[4], float (&im)[4]) {
    float dr  = bit ? u[6] : u[0], di = bit ? u[7] : u[1];
    float orr = bit ? u[4] : u[2], oi = bit ? u[5] : u[3];
#pragma unroll
    for (int j = 0; j < 4; j++) {
        float pr = __shfl_xor(re[j], mask);
        float pi = __shfl_xor(im[j], mask);
        float nr = dr*re[j] - di*im[j] + orr*pr - oi*pi;
        float ni = dr*im[j] + di*re[j] + orr*pi + oi*pr;
        re[j] = nr; im[j] = ni;
    }
}

// mask-16 gate on VALU (permlane16_swap) — bit-exact vs cgate_shfl(...,16,...)
__device__ __forceinline__ void cgate_pl16(const float* __restrict__ u, int bit,
        int lane, float (&re)[4], float (&im)[4]) {
    float dr  = bit ? u[6] : u[0], di = bit ? u[7] : u[1];
    float orr = bit ? u[4] : u[2], oi = bit ? u[5] : u[3];
#pragma unroll
    for (int j = 0; j < 4; j++) {
        float pr = xor16_val(re[j], lane);
        float pi = xor16_val(im[j], lane);
        float nr = dr*re[j] - di*im[j] + orr*pr - oi*pi;
        float ni = dr*im[j] + di*re[j] + orr*pi + oi*pr;
        re[j] = nr; im[j] = ni;
    }
}

// mask-32 gate on VALU (permlane32_swap)
__device__ __forceinline__ void cgate_pl32(const float* __restrict__ u, int bit,
        int lane, float (&re)[4], float (&im)[4]) {
    float dr  = bit ? u[6] : u[0], di = bit ? u[7] : u[1];
    float orr = bit ? u[4] : u[2], oi = bit ? u[5] : u[3];
#pragma unroll
    for (int j = 0; j < 4; j++) {
        float pr = xor32_val(re[j], lane);
        float pi = xor32_val(im[j], lane);
        float nr = dr*re[j] - di*im[j] + orr*pr - oi*pi;
        float ni = dr*im[j] + di*re[j] + orr*pi + oi*pr;
        re[j] = nr; im[j] = ni;
    }
}

template <int CTRL>
__device__ __forceinline__ void cgate_dpp(const float* __restrict__ u, int bit,
        float (&re)[4], float (&im)[4]) {
    float dr  = bit ? u[6] : u[0], di = bit ? u[7] : u[1];
    float orr = bit ? u[4] : u[2], oi = bit ? u[5] : u[3];
#pragma unroll
    for (int j = 0; j < 4; j++) {
        float pr = dpp_xor<CTRL>(re[j]);
        float pi = dpp_xor<CTRL>(im[j]);
        float nr = dr*re[j] - di*im[j] + orr*pr - oi*pi;
        float ni = dr*im[j] + di*re[j] + orr*pi + oi*pr;
        re[j] = nr; im[j] = ni;
    }
}

__global__ __launch_bounds__(256) void qsim_kernel(
        const float* __restrict__ x, const float* __restrict__ proj_w,
        const float* __restrict__ qnn_w, const float* __restrict__ out_w,
        const float* __restrict__ out_b, float* __restrict__ out) {
    __shared__ float gl[NDEPTH * NQ * 8]; // fused RX*RY*RX per (layer,qubit)

    int tid = threadIdx.x;
    // ---- in-block gate table (verified precompute math, R2..R7) -----------
    if (tid < NDEPTH * NQ) {
        float t0 = 0.5f * qnn_w[tid * 3 + 0];
        float t1 = 0.5f * qnn_w[tid * 3 + 1];
        float t2 = 0.5f * qnn_w[tid * 3 + 2];
        float c0 = cosf(t0), s0 = sinf(t0);
        float c1 = cosf(t1), s1 = sinf(t1);
        float c2 = cosf(t2), s2 = sinf(t2);
        float m00r =  c1 * c0, m00i =  s1 * s0;
        float m01r = -s1 * c0, m01i = -c1 * s0;
        float m10r =  s1 * c0, m10i = -c1 * s0;
        float m11r =  c1 * c0, m11i = -s1 * s0;
        float* g = gl + tid * 8;
        g[0] =  c2 * m00r + s2 * m10i;  g[1] =  c2 * m00i - s2 * m10r;
        g[2] =  c2 * m01r + s2 * m11i;  g[3] =  c2 * m01i - s2 * m11r;
        g[4] =  s2 * m00i + c2 * m10r;  g[5] = -s2 * m00r + c2 * m10i;
        g[6] =  s2 * m01i + c2 * m11r;  g[7] = -s2 * m01r + c2 * m11i;
    }
    __syncthreads();

    int lane = tid & 63;
    int b = blockIdx.x * 4 + (tid >> 6);

    // ---- encoding dots: d[q] = x[b]·proj_w[q] (float4 + DPP reduce) --------
    const float4* xr4 = (const float4*)(x + (size_t)b * FEAT);
    float4 xa = xr4[lane], xb = xr4[lane + 64];
    float dq[8];
#pragma unroll
    for (int q = 0; q < 8; q++) {
        const float4* pw4 = (const float4*)(proj_w + q * FEAT);
        float4 wa = pw4[lane], wb = pw4[lane + 64];
        float acc = xa.x*wa.x + xa.y*wa.y + xa.z*wa.z + xa.w*wa.w
                  + xb.x*wb.x + xb.y*wb.y + xb.z*wb.z + xb.w*wb.w;
        dq[q] = wave_sum_bcast(acc);
    }
    // lane group g = lane>>3 computes sincos of half-angle for qubit g
    int qsel = lane >> 3;
    float a0 = (qsel & 4) ? dq[4] : dq[0];
    float a1 = (qsel & 4) ? dq[5] : dq[1];
    float a2 = (qsel & 4) ? dq[6] : dq[2];
    float a3 = (qsel & 4) ? dq[7] : dq[3];
    float b0 = (qsel & 2) ? a2 : a0;
    float b1 = (qsel & 2) ? a3 : a1;
    float dsel = (qsel & 1) ? b1 : b0;
    float th = fast_tanh(dsel) * 0.78539816339744830962f;
    float se = __sinf(th), ce = __cosf(th);
    float cq[8], sq[8];
#pragma unroll
    for (int q = 0; q < 8; q++) {
        cq[q] = bcastlane(ce, q * 8);
        sq[q] = bcastlane(se, q * 8);
    }

    // ---- encoding layer as product state -----------------------------------
    float F = 1.f;
#pragma unroll
    for (int q = 2; q < 8; q++) {
        int bit = (lane >> (q - 2)) & 1;
        F *= bit ? sq[q] : cq[q];
    }
    float re[4], im[4];
    re[0] = F * cq[0] * cq[1];
    re[1] = F * sq[0] * cq[1];
    re[2] = F * cq[0] * sq[1];
    re[3] = F * sq[0] * sq[1];
    im[0] = im[1] = im[2] = im[3] = 0.f;

    // ---- variational layers (verified R2/R7; masks 16,32 now on VALU) ------
#pragma unroll
    for (int l = 0; l < NDEPTH; l++) {
        const float* g = gl + l * NQ * 8;
        cgate_pair(g, re[0], im[0], re[1], im[1]);
        cgate_pair(g, re[2], im[2], re[3], im[3]);
        cgate_pair(g + 8,  re[0], im[0], re[2], im[2]);
        cgate_pair(g + 8,  re[1], im[1], re[3], im[3]);
        cgate_dpp<0xB1>(g + 16, lane & 1,        re, im);
        cgate_dpp<0x4E>(g + 24, (lane >> 1) & 1, re, im);
        cgate_shfl(g + 32, (lane >> 2) & 1, 4,  re, im);
        cgate_shfl(g + 40, (lane >> 3) & 1, 8,  re, im);
        cgate_pl16(g + 48, (lane >> 4) & 1, lane, re, im);
        cgate_pl32(g + 56, (lane >> 5) & 1, lane, re, im);
        // CNOT ladder (verified R2/R7)
        { float t = re[1]; re[1] = re[3]; re[3] = t;
          t = im[1]; im[1] = im[3]; im[3] = t; }
        int base  = lane ^ ((lane << 1) & 63);
        int base2 = base ^ 1;
        re[0] = __shfl(re[0], base);  im[0] = __shfl(im[0], base);
        re[1] = __shfl(re[1], base);  im[1] = __shfl(im[1], base);
        re[2] = __shfl(re[2], base2); im[2] = __shfl(im[2], base2);
        re[3] = __shfl(re[3], base2); im[3] = __shfl(im[3], base2);
        int bit5 = (lane >> 5) & 1;
        {
            float t0 = bit5 ? re[1] : re[0], t1 = bit5 ? re[0] : re[1];
            float t2 = bit5 ? re[3] : re[2], t3 = bit5 ? re[2] : re[3];
            re[0] = t0; re[1] = t1; re[2] = t2; re[3] = t3;
            t0 = bit5 ? im[1] : im[0]; t1 = bit5 ? im[0] : im[1];
            t2 = bit5 ? im[3] : im[2]; t3 = bit5 ? im[2] : im[3];
            im[0] = t0; im[1] = t1; im[2] = t2; im[3] = t3;
        }
    }

    // ---- PauliZ expectations (DPP reductions, verified R2/R7) --------------
    float p0 = re[0]*re[0] + im[0]*im[0];
    float p1 = re[1]*re[1] + im[1]*im[1];
    float p2 = re[2]*re[2] + im[2]*im[2];
    float p3 = re[3]*re[3] + im[3]*im[3];
    float pt = p0 + p1 + p2 + p3;
    float eq[8];
    eq[0] = wave_sum_bcast(p0 - p1 + p2 - p3);
    eq[1] = wave_sum_bcast(p0 + p1 - p2 - p3);
#pragma unroll
    for (int q = 2; q < 8; q++) {
        int bit = (lane >> (q - 2)) & 1;
        eq[q] = wave_sum_bcast(bit ? -pt : pt);
    }

    // ---- output head -------------------------------------------------------
    if (lane < NCLS) {
        const float* wrow = out_w + lane * NQ;
        float acc = out_b[lane];
#pragma unroll
        for (int q = 0; q < 8; q++) acc = fmaf(eq[q], wrow[q], acc);
        out[(size_t)b * NCLS + lane] = acc;
    }
}

extern "C" void kernel_launch(void* const* d_in, const int* in_sizes, int n_in,
                              void* d_out, int out_size, void* d_ws, size_t ws_size,
                              hipStream_t stream) {
    const float* x      = (const float*)d_in[0];
    const float* proj_w = (const float*)d_in[1];
    const float* qnn_w  = (const float*)d_in[2];
    const float* out_w  = (const float*)d_in[3];
    const float* out_b  = (const float*)d_in[4];
    float* out = (float*)d_out;

    qsim_kernel<<<NBATCH / 4, 256, 0, stream>>>(x, proj_w, qnn_w, out_w, out_b, out);
}

// Round 9
// 84.851 us; speedup vs baseline: 1.0214x; 1.0214x over previous
//
#include <hip/hip_runtime.h>
#include <math.h>

#define NQ 8
#define NDEPTH 3
#define FEAT 512
#define NCLS 10
#define NBATCH 8192

// ---------------------------------------------------------------------------
// R7 structure (83.7 µs best, absmax 3.9e-3) with two algebraic rewrites:
//  - encoding dot reduction: transposed multi-value butterfly (q -> lane group)
//  - PauliZ expectations: single Walsh-Hadamard butterfly for eq[2..7]
// State layout: amp index = lane*4 + j ; j = qubits 0,1 ; lane bits = qubits 2..7.
// ---------------------------------------------------------------------------

// DPP helpers (HW-verified R2..R8)
template <int CTRL, int ROW_MASK>
__device__ __forceinline__ float dpp_term(float v) {
    return __int_as_float(__builtin_amdgcn_update_dpp(
        0, __float_as_int(v), CTRL, ROW_MASK, 0xf, true));
}

__device__ __forceinline__ float wave_sum_bcast(float v) {
    v += dpp_term<0x111, 0xf>(v); // row_shr:1
    v += dpp_term<0x112, 0xf>(v); // row_shr:2
    v += dpp_term<0x114, 0xf>(v); // row_shr:4
    v += dpp_term<0x118, 0xf>(v); // row_shr:8
    v += dpp_term<0x142, 0xa>(v); // row_bcast15
    v += dpp_term<0x143, 0xc>(v); // row_bcast31
    return __int_as_float(__builtin_amdgcn_readlane(__float_as_int(v), 63));
}

__device__ __forceinline__ float bcastlane(float v, int srclane) {
    return __int_as_float(__builtin_amdgcn_readlane(__float_as_int(v), srclane));
}

template <int CTRL>
__device__ __forceinline__ float dpp_xor(float v) {
    return __int_as_float(__builtin_amdgcn_update_dpp(
        0, __float_as_int(v), CTRL, 0xf, 0xf, true));
}

__device__ __forceinline__ float fast_tanh(float v) {
    float e = __expf(2.f * v);
    return 1.f - 2.f / (e + 1.f);
}

// Gate application (HW-verified R2..R8)
__device__ __forceinline__ void cgate_pair(const float* __restrict__ u,
        float& r0, float& i0, float& r1, float& i1) {
    float nr0 = u[0]*r0 - u[1]*i0 + u[2]*r1 - u[3]*i1;
    float ni0 = u[0]*i0 + u[1]*r0 + u[2]*i1 + u[3]*r1;
    float nr1 = u[4]*r0 - u[5]*i0 + u[6]*r1 - u[7]*i1;
    float ni1 = u[4]*i0 + u[5]*r0 + u[6]*i1 + u[7]*r1;
    r0 = nr0; i0 = ni0; r1 = nr1; i1 = ni1;
}

__device__ __forceinline__ void cgate_shfl(const float* __restrict__ u, int bit,
        int mask, float (&re)[4], float (&im)[4]) {
    float dr  = bit ? u[6] : u[0], di = bit ? u[7] : u[1];
    float orr = bit ? u[4] : u[2], oi = bit ? u[5] : u[3];
#pragma unroll
    for (int j = 0; j < 4; j++) {
        float pr = __shfl_xor(re[j], mask);
        float pi = __shfl_xor(im[j], mask);
        float nr = dr*re[j] - di*im[j] + orr*pr - oi*pi;
        float ni = dr*im[j] + di*re[j] + orr*pi + oi*pr;
        re[j] = nr; im[j] = ni;
    }
}

template <int CTRL>
__device__ __forceinline__ void cgate_dpp(const float* __restrict__ u, int bit,
        float (&re)[4], float (&im)[4]) {
    float dr  = bit ? u[6] : u[0], di = bit ? u[7] : u[1];
    float orr = bit ? u[4] : u[2], oi = bit ? u[5] : u[3];
#pragma unroll
    for (int j = 0; j < 4; j++) {
        float pr = dpp_xor<CTRL>(re[j]);
        float pi = dpp_xor<CTRL>(im[j]);
        float nr = dr*re[j] - di*im[j] + orr*pr - oi*pi;
        float ni = dr*im[j] + di*re[j] + orr*pi + oi*pr;
        re[j] = nr; im[j] = ni;
    }
}

__global__ __launch_bounds__(256) void qsim_kernel(
        const float* __restrict__ x, const float* __restrict__ proj_w,
        const float* __restrict__ qnn_w, const float* __restrict__ out_w,
        const float* __restrict__ out_b, float* __restrict__ out) {
    __shared__ float gl[NDEPTH * NQ * 8]; // fused RX*RY*RX per (layer,qubit)

    int tid = threadIdx.x;
    // ---- in-block gate table (verified precompute math, R2..R8) -----------
    if (tid < NDEPTH * NQ) {
        float t0 = 0.5f * qnn_w[tid * 3 + 0];
        float t1 = 0.5f * qnn_w[tid * 3 + 1];
        float t2 = 0.5f * qnn_w[tid * 3 + 2];
        float c0 = cosf(t0), s0 = sinf(t0);
        float c1 = cosf(t1), s1 = sinf(t1);
        float c2 = cosf(t2), s2 = sinf(t2);
        float m00r =  c1 * c0, m00i =  s1 * s0;
        float m01r = -s1 * c0, m01i = -c1 * s0;
        float m10r =  s1 * c0, m10i = -c1 * s0;
        float m11r =  c1 * c0, m11i = -s1 * s0;
        float* g = gl + tid * 8;
        g[0] =  c2 * m00r + s2 * m10i;  g[1] =  c2 * m00i - s2 * m10r;
        g[2] =  c2 * m01r + s2 * m11i;  g[3] =  c2 * m01i - s2 * m11r;
        g[4] =  s2 * m00i + c2 * m10r;  g[5] = -s2 * m00r + c2 * m10i;
        g[6] =  s2 * m01i + c2 * m11r;  g[7] = -s2 * m01r + c2 * m11i;
    }
    __syncthreads();

    int lane = tid & 63;
    int b = blockIdx.x * 4 + (tid >> 6);

    // ---- encoding dots: d[q] = x[b]·proj_w[q] ------------------------------
    const float4* xr4 = (const float4*)(x + (size_t)b * FEAT);
    float4 xa = xr4[lane], xb = xr4[lane + 64];
    float acc[8];
#pragma unroll
    for (int q = 0; q < 8; q++) {
        const float4* pw4 = (const float4*)(proj_w + q * FEAT);
        float4 wa = pw4[lane], wb = pw4[lane + 64];
        acc[q] = xa.x*wa.x + xa.y*wa.y + xa.z*wa.z + xa.w*wa.w
               + xb.x*wb.x + xb.y*wb.y + xb.z*wb.z + xb.w*wb.w;
    }
    // Transposed multi-value reduction: lane group g (= lane>>3) ends with
    // d[g] in all 8 of its lanes. Send-complement trick at each halving stage.
    int bit5 = (lane >> 5) & 1, bit4 = (lane >> 4) & 1, bit3 = (lane >> 3) & 1;
    float a2[4];
#pragma unroll
    for (int k = 0; k < 4; k++) {
        float u = bit5 ? acc[k] : acc[k + 4];       // what my partner keeps
        float r = __shfl_xor(u, 32);
        a2[k] = (bit5 ? acc[k + 4] : acc[k]) + r;   // q = k + 4*bit5
    }
    float a3[2];
#pragma unroll
    for (int k = 0; k < 2; k++) {
        float u = bit4 ? a2[k] : a2[k + 2];
        float r = __shfl_xor(u, 16);
        a3[k] = (bit4 ? a2[k + 2] : a2[k]) + r;     // q = k + 2*bit4 + 4*bit5
    }
    float u8 = bit3 ? a3[0] : a3[1];
    float f = (bit3 ? a3[1] : a3[0]) + __shfl_xor(u8, 8); // q = lane>>3
    // finish: butterfly within the 8-lane group -> all lanes hold d[lane>>3]
    f += __shfl_xor(f, 4);
    f += dpp_xor<0x4E>(f);
    f += dpp_xor<0xB1>(f);

    float th = fast_tanh(f) * 0.78539816339744830962f; // half-angle
    float se = __sinf(th), ce = __cosf(th);
    float cq[8], sq[8];
#pragma unroll
    for (int q = 0; q < 8; q++) {
        cq[q] = bcastlane(ce, q * 8);
        sq[q] = bcastlane(se, q * 8);
    }

    // ---- encoding layer as product state -----------------------------------
    float F = 1.f;
#pragma unroll
    for (int q = 2; q < 8; q++) {
        int bit = (lane >> (q - 2)) & 1;
        F *= bit ? sq[q] : cq[q];
    }
    float re[4], im[4];
    re[0] = F * cq[0] * cq[1];
    re[1] = F * sq[0] * cq[1];
    re[2] = F * cq[0] * sq[1];
    re[3] = F * sq[0] * sq[1];
    im[0] = im[1] = im[2] = im[3] = 0.f;

    // ---- variational layers (verbatim verified R2/R7) ----------------------
#pragma unroll
    for (int l = 0; l < NDEPTH; l++) {
        const float* g = gl + l * NQ * 8;
        cgate_pair(g, re[0], im[0], re[1], im[1]);
        cgate_pair(g, re[2], im[2], re[3], im[3]);
        cgate_pair(g + 8,  re[0], im[0], re[2], im[2]);
        cgate_pair(g + 8,  re[1], im[1], re[3], im[3]);
        cgate_dpp<0xB1>(g + 16, lane & 1,        re, im);
        cgate_dpp<0x4E>(g + 24, (lane >> 1) & 1, re, im);
        cgate_shfl(g + 32, (lane >> 2) & 1, 4,  re, im);
        cgate_shfl(g + 40, (lane >> 3) & 1, 8,  re, im);
        cgate_shfl(g + 48, (lane >> 4) & 1, 16, re, im);
        cgate_shfl(g + 56, (lane >> 5) & 1, 32, re, im);
        // CNOT ladder
        { float t = re[1]; re[1] = re[3]; re[3] = t;
          t = im[1]; im[1] = im[3]; im[3] = t; }
        int base  = lane ^ ((lane << 1) & 63);
        int base2 = base ^ 1;
        re[0] = __shfl(re[0], base);  im[0] = __shfl(im[0], base);
        re[1] = __shfl(re[1], base);  im[1] = __shfl(im[1], base);
        re[2] = __shfl(re[2], base2); im[2] = __shfl(im[2], base2);
        re[3] = __shfl(re[3], base2); im[3] = __shfl(im[3], base2);
        int b5 = (lane >> 5) & 1;
        {
            float t0 = b5 ? re[1] : re[0], t1 = b5 ? re[0] : re[1];
            float t2 = b5 ? re[3] : re[2], t3 = b5 ? re[2] : re[3];
            re[0] = t0; re[1] = t1; re[2] = t2; re[3] = t3;
            t0 = b5 ? im[1] : im[0]; t1 = b5 ? im[0] : im[1];
            t2 = b5 ? im[3] : im[2]; t3 = b5 ? im[2] : im[3];
            im[0] = t0; im[1] = t1; im[2] = t2; im[3] = t3;
        }
    }

    // ---- PauliZ expectations -----------------------------------------------
    float p0 = re[0]*re[0] + im[0]*im[0];
    float p1 = re[1]*re[1] + im[1]*im[1];
    float p2 = re[2]*re[2] + im[2]*im[2];
    float p3 = re[3]*re[3] + im[3]*im[3];
    float pt = p0 + p1 + p2 + p3;
    float eq[8];
    eq[0] = wave_sum_bcast(p0 - p1 + p2 - p3); // sign by in-reg bit 0
    eq[1] = wave_sum_bcast(p0 + p1 - p2 - p3); // sign by in-reg bit 1
    // Walsh-Hadamard butterfly on pt: lane (1<<(q-2)) ends with eq[q]
    {
        float p;
        p = dpp_xor<0xB1>(pt);  pt = (lane & 1)  ? (p - pt) : (pt + p);
        p = dpp_xor<0x4E>(pt);  pt = (lane & 2)  ? (p - pt) : (pt + p);
        p = __shfl_xor(pt, 4);  pt = (lane & 4)  ? (p - pt) : (pt + p);
        p = __shfl_xor(pt, 8);  pt = (lane & 8)  ? (p - pt) : (pt + p);
        p = __shfl_xor(pt, 16); pt = (lane & 16) ? (p - pt) : (pt + p);
        p = __shfl_xor(pt, 32); pt = (lane & 32) ? (p - pt) : (pt + p);
    }
    eq[2] = bcastlane(pt, 1);
    eq[3] = bcastlane(pt, 2);
    eq[4] = bcastlane(pt, 4);
    eq[5] = bcastlane(pt, 8);
    eq[6] = bcastlane(pt, 16);
    eq[7] = bcastlane(pt, 32);

    // ---- output head -------------------------------------------------------
    if (lane < NCLS) {
        const float* wrow = out_w + lane * NQ;
        float acc2 = out_b[lane];
#pragma unroll
        for (int q = 0; q < 8; q++) acc2 = fmaf(eq[q], wrow[q], acc2);
        out[(size_t)b * NCLS + lane] = acc2;
    }
}

extern "C" void kernel_launch(void* const* d_in, const int* in_sizes, int n_in,
                              void* d_out, int out_size, void* d_ws, size_t ws_size,
                              hipStream_t stream) {
    const float* x      = (const float*)d_in[0];
    const float* proj_w = (const float*)d_in[1];
    const float* qnn_w  = (const float*)d_in[2];
    const float* out_w  = (const float*)d_in[3];
    const float* out_b  = (const float*)d_in[4];
    float* out = (float*)d_out;

    qsim_kernel<<<NBATCH / 4, 256, 0, stream>>>(x, proj_w, qnn_w, out_w, out_b, out);
}